// Round 7
// baseline (122.672 us; speedup 1.0000x reference)
//
#include <hip/hip_runtime.h>
#include <math.h>

// Problem constants
#define NXD 64
#define NYD 48
#define NZD 32
#define NPT (NXD*NYD*NZD)   // 98304 points
#define PN  10              // neighbors per point
#define MF  5               // fourier modes
#define H1  64
#define H2  32
#define H3  8

// Block geometry: 256 threads = 4 waves; 32 points = 320 rows per block;
// each wave owns 8 points = 80 rows = 5 tiles of 16 rows, processed as
// 2 pipelined pairs + 1 tail tile (2-tile ILP to hide LDS/MFMA/trans latency).
#define PTS_PER_BLOCK 32
#define ROWS_PER_BLOCK (PTS_PER_BLOCK*PN)   // 320
#define TILES_PER_WAVE 5

// LDS strides (f16 elements) — row stride multiple of 8 (16B) for ds_read_b128
#define A2S 72   // 16 rows x 72 (64 ch + pad)
#define A3S 40   // 16 rows x 40 (32 ch + pad) — ALIASED into a2buf's space

#define INV2PI 0.15915494309189535f

typedef __attribute__((ext_vector_type(8))) _Float16 half8;   // 8 f16 = 4 VGPRs
typedef __attribute__((ext_vector_type(2))) _Float16 half2v;
typedef __attribute__((ext_vector_type(2))) __fp16   fp16x2;  // cvt_pkrtz return type
typedef __attribute__((ext_vector_type(2))) short    shortv2;
typedef __attribute__((ext_vector_type(4))) float    f32x4;

// pack two f32 -> half2v via v_cvt_pkrtz_f16_f32 (1 instr), bit-cast to _Float16 vec
__device__ __forceinline__ half2v cvt_pk_h2(float lo, float hi) {
    fp16x2 p = __builtin_amdgcn_cvt_pkrtz(lo, hi);
    return __builtin_bit_cast(half2v, p);
}

// Per-(lg,j) feature descriptor for the PERMUTED K-ordering of layer 1.
//   lg0: [x,   s0x,s1x,s2x,s3x,s4x, c0x,c1x]            (cA=x, cB=x)
//   lg1: [y,   c2x,c3x,c4x, s0y,s1y,s2y,s3y]            (cA=x, cB=y)
//   lg2: [z,   s4y, c0y,c1y,c2y,c3y,c4y, s0z]           (cA=y, cB=z)
//   lg3: [s1z,s2z,s3z,s4z, c0z,c1z,c2z,c3z]             (cA=z, cB=z)
// leftover channel 32 = c4z (rank-1 fixup).
// encoding: row(6b) | m(3b)<<6 | path(1b)<<9 | type(2b)<<10  (0=sin,1=cos,2=raw)
static __device__ const unsigned short kSlotTab[32] = {
  2048,    3,   70,  137,  204,  271, 1042, 1109,   // lg0
  2561, 1176, 1243, 1310,  516,  583,  650,  717,   // lg1
  2562,  272, 1043, 1110, 1177, 1244, 1311,  517,   // lg2
    72,  139,  206,  273, 1044, 1111, 1178, 1245 }; // lg3

// hardware f16 exp2 (trans pipe, 1 instr)
__device__ __forceinline__ _Float16 exp2h(_Float16 v) {
    _Float16 r;
    asm("v_exp_f16 %0, %1" : "=v"(r) : "v"(v));
    return r;
}

// Packed-f16 GELU on a pair of f32 pre-activations.
// gelu = x - x/(1+2^t), t = x*(2.3022082 + 0.10294324 x^2)  [tanh-form, log2e folded]
// reciprocal via f16 bit-trick guess (0x7800 - bits(y); exact at y=1,2; max err 12.5%)
// + 2 Newton steps -> 2.4e-4 rel. t clamped <=14 keeps y=1+2^t normal f16;
// t very negative -> E=0 -> y=1 -> r=1 -> gelu=0 exactly. 13 VALU + 2 trans per PAIR.
__device__ __forceinline__ half2v gelu_pk(float lo, float hi) {
    const _Float16 C1 = (_Float16)2.3022082f, C2 = (_Float16)0.10294324f;
    const half2v x  = cvt_pk_h2(lo, hi);
    const half2v x2 = x * x;
    half2v t = x * __builtin_elementwise_fma(x2, (half2v){C2, C2}, (half2v){C1, C1});
    t = __builtin_elementwise_min(t, (half2v){(_Float16)14.0f, (_Float16)14.0f});
    const _Float16 e0 = exp2h(t[0]);
    const _Float16 e1 = exp2h(t[1]);
    const half2v one = {(_Float16)1.0f, (_Float16)1.0f};
    const half2v two = {(_Float16)2.0f, (_Float16)2.0f};
    const half2v y = (half2v){e0, e1} + one;
    const shortv2 rb = (shortv2){(short)0x7800, (short)0x7800} - __builtin_bit_cast(shortv2, y);
    half2v r = __builtin_bit_cast(half2v, rb);
    r = r * __builtin_elementwise_fma(-y, r, two);
    r = r * __builtin_elementwise_fma(-y, r, two);
    return x - x * r;
}

// tanh via 2^x: 1 - 2/(1+2^{2*log2e*v}); safe at both infinities
__device__ __forceinline__ float tanh_fast(float v) {
    float E = __builtin_amdgcn_exp2f(2.8853901f * v);
    return 1.0f - 2.0f * __builtin_amdgcn_rcpf(E + 1.0f);
}

__global__ __launch_bounds__(256) void domino_mfma_kernel(
    const float* __restrict__ x,      // (NPT*PN, 3)
    const float* __restrict__ freqs,  // (MF,)
    const float* __restrict__ W1,     // (33, 64)
    const float* __restrict__ b1,
    const float* __restrict__ W2,     // (64, 32)
    const float* __restrict__ b2,
    const float* __restrict__ W3,     // (32, 8)
    const float* __restrict__ b3,
    float* __restrict__ out)          // (8, NPT)
{
    // LDS budget (sum 29888 B -> 5 blocks/CU = 20 waves/CU, above measured residency):
    __shared__ __align__(16) _Float16 a2buf[4][2][16 * A2S];    // 18432 B; low bytes alias a3
    __shared__ __align__(16) float cbuf[976];                   // 3904 B staged coords
    __shared__ __align__(16) _Float16 obuf[ROWS_PER_BLOCK * 9]; // 5760 B masked tanh rows
    __shared__ __align__(16) float mcx[4][2][16];               // x-coordinate per row (mask)
    __shared__ __align__(16) float mv32[4][2][16];              // feature ch32 = cos(f4*z)
    __shared__ __align__(16) float coefA[2][32];                // (x2 copies: (tp&1) anti-hoist)
    __shared__ __align__(16) float coefB[2][32];
    __shared__ __align__(16) float coefO[2][32];

    const int tid  = threadIdx.x;
    const int w    = tid >> 6;      // wave id 0..3
    const int lane = tid & 63;
    const int lr   = lane & 15;     // A-row / B-col / C-col index
    const int lg   = lane >> 4;     // k-group / C-row-group

    const int wrow0 = blockIdx.x * ROWS_PER_BLOCK + w * (TILES_PER_WAVE*16);

    // ---- fill per-lg coefficient tables (32 threads; duplicated for (tp&1) indexing)
    if (tid < 32) {
        const unsigned e = kSlotTab[tid];
        const int m = (e >> 6) & 7, path = (e >> 9) & 1, ty = (e >> 10) & 3;
        const float fm = freqs[m] * INV2PI;
        const float fa = (ty != 2 && path == 0) ? fm : 0.0f;
        const float fb = (ty != 2 && path == 1) ? fm : 0.0f;
        const float fo = (ty == 1) ? 0.25f : 0.0f;
        coefA[0][tid] = fa; coefA[1][tid] = fa;
        coefB[0][tid] = fb; coefB[1][tid] = fb;
        coefO[0][tid] = fo; coefO[1][tid] = fo;
    }

    // ---- stage this wave's 80 coord rows (960 B) into LDS: one global_load_lds dwordx4.
    // Lanes 60-63 overflow 64B into the next wave's region with IDENTICAL data (benign);
    // wave 3 clamps its tail lanes (writes land in the 64B slack, never read).
    {
        const int sl = (w == 3 && lane >= 60) ? 59 : lane;
        const float* gsrc = x + (size_t)wrow0 * 3 + (size_t)sl * 4;
        __builtin_amdgcn_global_load_lds(
            (const __attribute__((address_space(1))) void*)gsrc,
            (__attribute__((address_space(3))) void*)&cbuf[w * 240], 16, 0, 0);
    }

    const float f4rev = freqs[4] * INV2PI;
    const float rawf  = (lg < 3) ? 1.0f : 0.0f;   // slot0 is a raw coordinate for lg0..2

    // ---- preload weight fragments as f16 (once per wave)
    // B layout for 16x16x32: n = lane&15, k = (lane>>4)*8 + j ; k -> W1 row via slot table
    half8 B1f[4];                       // layer1: K=32 (permuted), N=64 -> 4 n-tiles
    float  w32[4], bv1[4];              // ch32 rank-1 fixup weights + bias
    #pragma unroll
    for (int t1 = 0; t1 < 4; ++t1) {
        #pragma unroll
        for (int j = 0; j < 8; ++j) {
            const int row = kSlotTab[lg*8 + j] & 63;
            B1f[t1][j] = (_Float16)W1[row*H1 + t1*16 + lr];
        }
        w32[t1] = W1[32*H1 + t1*16 + lr];
        bv1[t1] = b1[t1*16 + lr];
    }
    half8 B2f[2][2];                    // layer2: K=64 (2 steps), N=32 -> 2 n-tiles
    float  bv2[2];
    #pragma unroll
    for (int s = 0; s < 2; ++s)
        #pragma unroll
        for (int t2 = 0; t2 < 2; ++t2)
            #pragma unroll
            for (int j = 0; j < 8; ++j)
                B2f[s][t2][j] = (_Float16)W2[(s*32 + lg*8 + j)*H2 + t2*16 + lr];
    #pragma unroll
    for (int t2 = 0; t2 < 2; ++t2) bv2[t2] = b2[t2*16 + lr];

    half8 B3f;                          // layer3: K=32, N=16 (cols 8..15 zero)
    float  bv3 = (lr < H3) ? b3[lr] : 0.0f;
    #pragma unroll
    for (int j = 0; j < 8; ++j)
        B3f[j] = (lr < H3) ? (_Float16)W3[(lg*8 + j)*H3 + lr] : (_Float16)0.0f;

    // tables + staged coords visible to all waves (implies vmcnt/lgkmcnt drain)
    __syncthreads();

    // ================= phase helpers (inlined; u is always a literal) =================
    auto featgen = [&](int t, int u,
                       const f32x4& fa0, const f32x4& fb0, const f32x4& fo0,
                       const f32x4& fa1, const f32x4& fb1, const f32x4& fo1) -> half8 {
        const int cfx = w*240 + (t*16 + lr)*3;
        const float cx = cbuf[cfx + 0];
        const float cy = cbuf[cfx + 1];
        const float cz = cbuf[cfx + 2];
        const float cA = (lg <= 1) ? cx : ((lg == 2) ? cy : cz);
        const float cB = (lg == 0) ? cx : ((lg == 1) ? cy : cz);
        float fv[8];
        #pragma unroll
        for (int j = 0; j < 4; ++j) {
            float rev = cA*fa0[j] + (cB*fb0[j] + fo0[j]);
            fv[j] = __builtin_amdgcn_sinf(__builtin_amdgcn_fractf(rev));
        }
        #pragma unroll
        for (int j = 0; j < 4; ++j) {
            float rev = cA*fa1[j] + (cB*fb1[j] + fo1[j]);
            fv[4+j] = __builtin_amdgcn_sinf(__builtin_amdgcn_fractf(rev));
        }
        fv[0] += rawf * (cB - fv[0]);   // slot0 raw-coordinate override (no-op for lg3)
        if (lg == 0) {
            mcx[w][u][lr]  = cx;
            mv32[w][u][lr] = __builtin_amdgcn_sinf(__builtin_amdgcn_fractf(cz * f4rev + 0.25f));
        }
        union { half2v h2[4]; half8 h8; } a1u;
        #pragma unroll
        for (int j = 0; j < 4; ++j)
            a1u.h2[j] = cvt_pk_h2(fv[2*j], fv[2*j+1]);
        return a1u.h8;
    };

    auto layer1 = [&](const half8& a1, f32x4* c1, int u) {
        #pragma unroll
        for (int t1 = 0; t1 < 4; ++t1) {
            f32x4 ci = {bv1[t1], bv1[t1], bv1[t1], bv1[t1]};
            c1[t1] = __builtin_amdgcn_mfma_f32_16x16x32_f16(a1, B1f[t1], ci, 0, 0, 0);
        }
        const f32x4 v32r = *(const f32x4*)&mv32[w][u][lg*4];
        #pragma unroll
        for (int t1 = 0; t1 < 4; ++t1)
            #pragma unroll
            for (int r = 0; r < 4; ++r)
                c1[t1][r] += v32r[r] * w32[t1];
    };

    auto gelu_a2 = [&](const f32x4* c1, int u) {
        _Float16* const buf = &a2buf[w][u][0];
        #pragma unroll
        for (int t1 = 0; t1 < 4; ++t1) {
            const half2v g01 = gelu_pk(c1[t1][0], c1[t1][1]);
            const half2v g23 = gelu_pk(c1[t1][2], c1[t1][3]);
            const int col = t1*16 + lr;
            buf[(lg*4 + 0)*A2S + col] = g01[0];
            buf[(lg*4 + 1)*A2S + col] = g01[1];
            buf[(lg*4 + 2)*A2S + col] = g23[0];
            buf[(lg*4 + 3)*A2S + col] = g23[1];
        }
    };

    auto read_a2 = [&](int u, half8* a2f) {
        #pragma unroll
        for (int s = 0; s < 2; ++s)
            a2f[s] = *(const half8*)&a2buf[w][u][lr*A2S + s*32 + lg*8];
    };

    auto layer2 = [&](const half8* a2f, f32x4* c2) {
        #pragma unroll
        for (int t2 = 0; t2 < 2; ++t2) {
            f32x4 ci = {bv2[t2], bv2[t2], bv2[t2], bv2[t2]};
            ci = __builtin_amdgcn_mfma_f32_16x16x32_f16(a2f[0], B2f[0][t2], ci, 0, 0, 0);
            c2[t2] = __builtin_amdgcn_mfma_f32_16x16x32_f16(a2f[1], B2f[1][t2], ci, 0, 0, 0);
        }
    };

    // a3 region ALIASES a2buf[w][u] rows 0..8: safe — a2f reads completed (data-dep
    // through L2 MFMA) before these writes issue; same-wave LDS ops are in-order.
    auto gelu_a3 = [&](const f32x4* c2, int u) {
        _Float16* const a3p = &a2buf[w][u][0];
        #pragma unroll
        for (int t2 = 0; t2 < 2; ++t2) {
            const half2v g01 = gelu_pk(c2[t2][0], c2[t2][1]);
            const half2v g23 = gelu_pk(c2[t2][2], c2[t2][3]);
            const int col = t2*16 + lr;
            a3p[(lg*4 + 0)*A3S + col] = g01[0];
            a3p[(lg*4 + 1)*A3S + col] = g01[1];
            a3p[(lg*4 + 2)*A3S + col] = g23[0];
            a3p[(lg*4 + 3)*A3S + col] = g23[1];
        }
    };

    auto l3_tail = [&](int t, int u) {
        const half8 a3f = *(const half8*)&a2buf[w][u][lr*A3S + lg*8];
        f32x4 c3 = {bv3, bv3, bv3, bv3};
        c3 = __builtin_amdgcn_mfma_f32_16x16x32_f16(a3f, B3f, c3, 0, 0, 0);
        const f32x4 mxr = *(const f32x4*)&mcx[w][u][lg*4];
        #pragma unroll
        for (int r = 0; r < 4; ++r) {
            const int brow = w*(TILES_PER_WAVE*16) + t*16 + lg*4 + r;
            const float mk = (fabsf(mxr[r]) > 1e-6f) ? 1.0f : 0.0f;
            if (lr < H3) obuf[brow*9 + lr] = (_Float16)(mk * tanh_fast(c3[r]));
        }
    };

    // ================= 2-tile pipelined pairs: (0,1), (2,3) =================
    #pragma unroll 1
    for (int tp = 0; tp < 2; ++tp) {
        const int tc = tp & 1;   // runtime-indexed copy blocks coef LICM across pairs
        const f32x4 fa0 = *(const f32x4*)&coefA[tc][lg*8];
        const f32x4 fb0 = *(const f32x4*)&coefB[tc][lg*8];
        const f32x4 fo0 = *(const f32x4*)&coefO[tc][lg*8];
        const f32x4 fa1 = *(const f32x4*)&coefA[tc][lg*8 + 4];
        const f32x4 fb1 = *(const f32x4*)&coefB[tc][lg*8 + 4];
        const f32x4 fo1 = *(const f32x4*)&coefO[tc][lg*8 + 4];

        const half8 a1a = featgen(2*tp + 0, 0, fa0, fb0, fo0, fa1, fb1, fo1);
        const half8 a1b = featgen(2*tp + 1, 1, fa0, fb0, fo0, fa1, fb1, fo1);

        f32x4 c1a[4], c1b[4];
        layer1(a1a, c1a, 0);
        layer1(a1b, c1b, 1);

        gelu_a2(c1a, 0);
        gelu_a2(c1b, 1);

        half8 a2fa[2], a2fb[2];
        read_a2(0, a2fa);
        read_a2(1, a2fb);

        f32x4 c2a[2], c2b[2];
        layer2(a2fa, c2a);
        layer2(a2fb, c2b);

        gelu_a3(c2a, 0);
        gelu_a3(c2b, 1);

        l3_tail(2*tp + 0, 0);
        l3_tail(2*tp + 1, 1);
    }

    // ================= tail tile 4 (single stream) =================
    {
        const f32x4 fa0 = *(const f32x4*)&coefA[0][lg*8];
        const f32x4 fb0 = *(const f32x4*)&coefB[0][lg*8];
        const f32x4 fo0 = *(const f32x4*)&coefO[0][lg*8];
        const f32x4 fa1 = *(const f32x4*)&coefA[0][lg*8 + 4];
        const f32x4 fb1 = *(const f32x4*)&coefB[0][lg*8 + 4];
        const f32x4 fo1 = *(const f32x4*)&coefO[0][lg*8 + 4];

        const half8 a1t = featgen(4, 0, fa0, fb0, fo0, fa1, fb1, fo1);
        f32x4 c1t[4];
        layer1(a1t, c1t, 0);
        gelu_a2(c1t, 0);
        half8 a2ft[2];
        read_a2(0, a2ft);
        f32x4 c2t[2];
        layer2(a2ft, c2t);
        gelu_a3(c2t, 0);
        l3_tail(4, 0);
    }

    __syncthreads();

    // ---- neighbor reduction: 32 points x 8 channels = 256 threads
    {
        const int p  = tid >> 3;   // 0..31
        const int ch = tid & 7;
        float sum = 0.0f;
        #pragma unroll
        for (int i = 0; i < PN; ++i) sum += (float)obuf[(p*PN + i)*9 + ch];
        const int gp = blockIdx.x * PTS_PER_BLOCK + p;
        out[(size_t)ch * NPT + gp] = sum;
    }
}

extern "C" void kernel_launch(void* const* d_in, const int* in_sizes, int n_in,
                              void* d_out, int out_size, void* d_ws, size_t ws_size,
                              hipStream_t stream) {
    // setup_inputs order: x, grid(unused), freqs, W1, b1, W2, b2, W3, b3
    const float* x     = (const float*)d_in[0];
    const float* freqs = (const float*)d_in[2];
    const float* W1    = (const float*)d_in[3];
    const float* b1    = (const float*)d_in[4];
    const float* W2    = (const float*)d_in[5];
    const float* b2    = (const float*)d_in[6];
    const float* W3    = (const float*)d_in[7];
    const float* b3    = (const float*)d_in[8];
    float* out = (float*)d_out;

    const int grid = NPT / PTS_PER_BLOCK;   // 3072 blocks, no remainder
    domino_mfma_kernel<<<grid, 256, 0, stream>>>(x, freqs, W1, b1, W2, b2, W3, b3, out);
}